// Round 9
// baseline (569.608 us; speedup 1.0000x reference)
//
#include <hip/hip_runtime.h>
#include <hip/hip_bf16.h>
#include <math.h>

// Problem constants
#define BB 4
#define LL 2048
#define DM 1024
#define DI 2048
#define DS 16
#define DR 64
#define KC 4
#define TT (BB * LL)   // 8192 tokens
#define NC 32          // scan chunks per sequence
#define CL (LL / NC)   // 64 steps per chunk
#define SK 8           // x_proj split-K factor
#define LOG2E 1.4426950408889634f

typedef __hip_bfloat16 bf16;
typedef short bf16x8 __attribute__((ext_vector_type(8)));
typedef short short8 __attribute__((ext_vector_type(8)));
typedef float f32x4 __attribute__((ext_vector_type(4)));
typedef float float4v __attribute__((ext_vector_type(4)));

__device__ __forceinline__ float cvt(float v) { return v; }
__device__ __forceinline__ float cvt(bf16 v) { return __bfloat162float(v); }
__device__ __forceinline__ float bf2f(short s) {
  union { short s; bf16 h; } c; c.s = s; return __bfloat162float(c.h);
}
__device__ __forceinline__ void stv(float* p, float v) { *p = v; }
__device__ __forceinline__ void stv(bf16* p, float v) { *p = __float2bfloat16(v); }
__device__ __forceinline__ short f2bf(float f) {
  union { bf16 h; short s; } u_; u_.h = __float2bfloat16(f); return u_.s;
}

// async global->LDS, 16B per lane; lds dest must be WAVE-UNIFORM base (HW adds lane*16)
__device__ __forceinline__ void gld16(const bf16* g, bf16* l) {
  __builtin_amdgcn_global_load_lds(
      (const __attribute__((address_space(1))) void*)g,
      (__attribute__((address_space(3))) void*)l, 16, 0, 0);
}

// ---------------------------------------------------------------------------
// f32 -> bf16 bulk convert (8 elems/thread, n8 = n/8)
// ---------------------------------------------------------------------------
__global__ __launch_bounds__(256) void cvt_bf16(
    const float* __restrict__ src, bf16* __restrict__ dst, int n8) {
  int i = blockIdx.x * 256 + threadIdx.x;
  if (i >= n8) return;
  const float4v* s = (const float4v*)(src + (size_t)i * 8);
  float4v v0 = s[0], v1 = s[1];
  short8 o;
#pragma unroll
  for (int j = 0; j < 4; ++j) { o[j] = f2bf(v0[j]); o[4 + j] = f2bf(v1[j]); }
  *(short8*)(dst + (size_t)i * 8) = o;
}

// ---------------------------------------------------------------------------
// Pure-bf16 MFMA GEMM, 2-phase double-buffered (unchanged from round 8).
// ---------------------------------------------------------------------------
template <typename TC>
__global__ __launch_bounds__(256) void gemm_bf16(
    const bf16* __restrict__ A, int lda,
    const bf16* __restrict__ W, int ldw,
    TC* __restrict__ C, int ldc, int Kd) {
  __shared__ bf16 As[2][128 * 32];
  __shared__ bf16 Bs[2][128 * 32];
  int tid = threadIdx.x;
  int bm = blockIdx.y * 128, bn = blockIdx.x * 128;
  int wave = tid >> 6, lane = tid & 63;
  int wm = (wave >> 1) * 64, wn = (wave & 1) * 64;
  int lr = lane & 15, kg = lane >> 4;

  int srow = wave * 16 + (lane >> 2);
  int kc = (lane & 3) * 8;
  const bf16* gA0 = A + (size_t)(bm + srow) * lda + kc;
  const bf16* gA1 = gA0 + (size_t)64 * lda;
  const bf16* gW0 = W + (size_t)(bn + srow) * ldw + kc;
  const bf16* gW1 = gW0 + (size_t)64 * ldw;

  f32x4 acc[4][4] = {};

#define STAGE_BF(p, k0)                              \
  do {                                               \
    gld16(gA0 + (k0), &As[p][wave * 512]);           \
    gld16(gA1 + (k0), &As[p][2048 + wave * 512]);    \
    gld16(gW0 + (k0), &Bs[p][wave * 512]);           \
    gld16(gW1 + (k0), &Bs[p][2048 + wave * 512]);    \
  } while (0)

#define COMPUTE_BF(p)                                                         \
  do {                                                                        \
    bf16x8 af[4], bfr[4];                                                     \
    _Pragma("unroll") for (int i = 0; i < 4; ++i)                             \
        af[i] = *(const bf16x8*)&As[p][(wm + i * 16 + lr) * 32 + kg * 8];     \
    _Pragma("unroll") for (int j = 0; j < 4; ++j)                             \
        bfr[j] = *(const bf16x8*)&Bs[p][(wn + j * 16 + lr) * 32 + kg * 8];    \
    _Pragma("unroll") for (int i = 0; i < 4; ++i)                             \
        _Pragma("unroll") for (int j = 0; j < 4; ++j)                         \
            acc[i][j] = __builtin_amdgcn_mfma_f32_16x16x32_bf16(              \
                af[i], bfr[j], acc[i][j], 0, 0, 0);                           \
  } while (0)

  STAGE_BF(0, 0);
  __syncthreads();
  int p = 0;
  for (int k0 = 0; k0 < Kd - 32; k0 += 32) {
    STAGE_BF(p ^ 1, k0 + 32);
    COMPUTE_BF(p);
    __syncthreads();
    p ^= 1;
  }
  COMPUTE_BF(p);

#pragma unroll
  for (int i = 0; i < 4; ++i) {
    int row0 = bm + wm + i * 16 + kg * 4;
#pragma unroll
    for (int j = 0; j < 4; ++j) {
      int col = bn + wn + j * 16 + lr;
#pragma unroll
      for (int rr = 0; rr < 4; ++rr)
        stv(&C[(size_t)(row0 + rr) * ldc + col], acc[i][j][rr]);
    }
  }
#undef STAGE_BF
#undef COMPUTE_BF
}

// ---------------------------------------------------------------------------
// Reg-staged MFMA GEMM with f32->bf16 convert (dt_proj) + bias+softplus epi.
// ---------------------------------------------------------------------------
__device__ __forceinline__ void loadcvt16(const float* p, short* d) {
#pragma unroll
  for (int i = 0; i < 4; ++i) {
    float4v v = ((const float4v*)p)[i];
#pragma unroll
    for (int j = 0; j < 4; ++j) d[i * 4 + j] = f2bf(v[j]);
  }
}
__device__ __forceinline__ void loadcvt16(const bf16* p, short* d) {
  ((short8*)d)[0] = ((const short8*)p)[0];
  ((short8*)d)[1] = ((const short8*)p)[1];
}

template <typename TA, typename TC, int EPI>
__global__ __launch_bounds__(256) void gemm_mfma(
    const TA* __restrict__ A, int lda,
    const float* __restrict__ W, int ldw,
    const float* __restrict__ bias,
    TC* __restrict__ C, int ldc, int Kd) {
  __shared__ short As[128 * 40];
  __shared__ short Bs[128 * 40];
  int tid = threadIdx.x;
  int bm = blockIdx.y * 128, bn = blockIdx.x * 128;

  int r = tid >> 1, hh = (tid & 1) * 16;
  const TA* ga = A + (size_t)(bm + r) * lda + hh;
  const float* gw = W + (size_t)(bn + r) * ldw + hh;

  int wave = tid >> 6, lane = tid & 63;
  int wm = (wave >> 1) * 64, wn = (wave & 1) * 64;
  int lr = lane & 15, kg = lane >> 4;

  f32x4 acc[4][4] = {};

  for (int k0 = 0; k0 < Kd; k0 += 32) {
    short abuf[16], wbuf[16];
    loadcvt16(ga + k0, abuf);
    loadcvt16(gw + k0, wbuf);
    __syncthreads();
    ((short8*)&As[r * 40 + hh])[0] = ((short8*)abuf)[0];
    ((short8*)&As[r * 40 + hh])[1] = ((short8*)abuf)[1];
    ((short8*)&Bs[r * 40 + hh])[0] = ((short8*)wbuf)[0];
    ((short8*)&Bs[r * 40 + hh])[1] = ((short8*)wbuf)[1];
    __syncthreads();

    bf16x8 af[4], bfr[4];
#pragma unroll
    for (int i = 0; i < 4; ++i)
      af[i] = *(const bf16x8*)&As[(wm + i * 16 + lr) * 40 + kg * 8];
#pragma unroll
    for (int j = 0; j < 4; ++j)
      bfr[j] = *(const bf16x8*)&Bs[(wn + j * 16 + lr) * 40 + kg * 8];
#pragma unroll
    for (int i = 0; i < 4; ++i)
#pragma unroll
      for (int j = 0; j < 4; ++j)
        acc[i][j] = __builtin_amdgcn_mfma_f32_16x16x32_bf16(af[i], bfr[j], acc[i][j], 0, 0, 0);
  }

#pragma unroll
  for (int i = 0; i < 4; ++i) {
    int row0 = bm + wm + i * 16 + kg * 4;
#pragma unroll
    for (int j = 0; j < 4; ++j) {
      int col = bn + wn + j * 16 + lr;
#pragma unroll
      for (int rr = 0; rr < 4; ++rr) {
        float v = acc[i][j][rr];
        if (EPI == 1) {
          v += bias[col];
          v = (v > 20.f) ? v : log1pf(expf(v));
        }
        stv(&C[(size_t)(row0 + rr) * ldc + col], v);
      }
    }
  }
}

// ---------------------------------------------------------------------------
// Scan-state / split-K partial aliasing into the dead x-half of xz.
// ---------------------------------------------------------------------------
__device__ __forceinline__ float* stslot(bf16* xz, int idx) {
  int t = idx >> 10, j = idx & 1023;
  return (float*)((char*)xz + (size_t)t * 8192) + j;
}
#define SUMD_BASE (8192 * NC * DS)

// ---------------------------------------------------------------------------
// x_proj split-K, bf16 weights (unchanged).
// ---------------------------------------------------------------------------
__global__ __launch_bounds__(256) void xproj_splitk(
    const bf16* __restrict__ u, const bf16* __restrict__ W,
    bf16* __restrict__ xz) {
  __shared__ short As[128 * 40];
  __shared__ short Bs[96 * 40];
  int tid = threadIdx.x;
  int bm = blockIdx.x * 128;
  int sk = blockIdx.y;
  int kb = sk * (DI / SK);

  int r = tid >> 1, hh = (tid & 1) * 16;
  const bf16* ga = u + (size_t)(bm + r) * DI + kb + hh;
  const bf16* gw = W + (size_t)r * DI + kb + hh;

  int wave = tid >> 6, lane = tid & 63;
  int wm = wave * 32;
  int lr = lane & 15, kg = lane >> 4;

  f32x4 acc[2][6] = {};

  for (int k0 = 0; k0 < DI / SK; k0 += 32) {
    short abuf[16], wbuf[16];
    loadcvt16(ga + k0, abuf);
    if (r < 96) loadcvt16(gw + k0, wbuf);
    __syncthreads();
    ((short8*)&As[r * 40 + hh])[0] = ((short8*)abuf)[0];
    ((short8*)&As[r * 40 + hh])[1] = ((short8*)abuf)[1];
    if (r < 96) {
      ((short8*)&Bs[r * 40 + hh])[0] = ((short8*)wbuf)[0];
      ((short8*)&Bs[r * 40 + hh])[1] = ((short8*)wbuf)[1];
    }
    __syncthreads();

    bf16x8 af[2], bfr[6];
#pragma unroll
    for (int i = 0; i < 2; ++i)
      af[i] = *(const bf16x8*)&As[(wm + i * 16 + lr) * 40 + kg * 8];
#pragma unroll
    for (int j = 0; j < 6; ++j)
      bfr[j] = *(const bf16x8*)&Bs[(j * 16 + lr) * 40 + kg * 8];
#pragma unroll
    for (int i = 0; i < 2; ++i)
#pragma unroll
      for (int j = 0; j < 6; ++j)
        acc[i][j] = __builtin_amdgcn_mfma_f32_16x16x32_bf16(af[i], bfr[j], acc[i][j], 0, 0, 0);
  }

#pragma unroll
  for (int i = 0; i < 2; ++i) {
#pragma unroll
    for (int j = 0; j < 6; ++j) {
      int col = j * 16 + lr;
#pragma unroll
      for (int rr = 0; rr < 4; ++rr) {
        int row = bm + wm + i * 16 + kg * 4 + rr;
        *stslot(xz, (sk * 8192 + row) * 96 + col) = acc[i][j][rr];
      }
    }
  }
}

__global__ __launch_bounds__(256) void xproj_reduce(
    bf16* __restrict__ xz, float* __restrict__ xdbl) {
  int gid = blockIdx.x * 256 + threadIdx.x;
  float s = 0.f;
#pragma unroll
  for (int sk = 0; sk < SK; ++sk)
    s += *stslot(xz, sk * (8192 * 96) + gid);
  xdbl[gid] = s;
}

// ---------------------------------------------------------------------------
// Depthwise causal conv1d (K=4) + bias + SiLU — vectorized (unchanged).
// ---------------------------------------------------------------------------
__global__ __launch_bounds__(256) void conv_silu(
    const bf16* __restrict__ xz, const float* __restrict__ cw,
    const float* __restrict__ cb, bf16* __restrict__ u) {
  int t = blockIdx.x;
  int d0 = threadIdx.x * 8;
  int l = t & (LL - 1);

  float acc[8];
  float4v c0 = *(const float4v*)&cb[d0];
  float4v c1 = *(const float4v*)&cb[d0 + 4];
#pragma unroll
  for (int j = 0; j < 4; ++j) { acc[j] = c0[j]; acc[4 + j] = c1[j]; }

  float wv[32];
  const float4v* wp = (const float4v*)&cw[d0 * 4];
#pragma unroll
  for (int q = 0; q < 8; ++q) {
    float4v v = wp[q];
#pragma unroll
    for (int j = 0; j < 4; ++j) wv[q * 4 + j] = v[j];
  }

#pragma unroll
  for (int k = 0; k < KC; ++k) {
    int lt = l - (KC - 1) + k;
    if (lt >= 0) {
      short8 xv = *(const short8*)&xz[(size_t)(t - (KC - 1) + k) * (2 * DI) + d0];
#pragma unroll
      for (int q = 0; q < 8; ++q)
        acc[q] = fmaf(bf2f(xv[q]), wv[q * 4 + k], acc[q]);
    }
  }

  short8 ov;
#pragma unroll
  for (int q = 0; q < 8; ++q) {
    float s = acc[q] / (1.f + __expf(-acc[q]));
    ov[q] = f2bf(s);
  }
  *(short8*)&u[(size_t)t * DI + d0] = ov;
}

// ---------------------------------------------------------------------------
// Chunked selective scan, thread-per-chain, LDS-staged B/C panels,
// exp2 with prescaled A, explicit pointer increments.
// Block = 256 threads = 256 consecutive d's, same (b,c) -> same B/C rows.
// ---------------------------------------------------------------------------
__global__ __launch_bounds__(256) void scan_local(
    const bf16* __restrict__ delta, const bf16* __restrict__ u,
    const float* __restrict__ xdbl, bf16* __restrict__ xz,
    const float* __restrict__ A_log) {
  __shared__ float lds_b[CL * DS];   // 64 x 16 f32 = 4 KB
  int tid = threadIdx.x;
  int g = blockIdx.x * 256 + tid;
  int d = g & (DI - 1);
  int b = (g >> 11) & (BB - 1);
  int c = g >> 13;
  int chain = (b << 11) | d;
  int t0 = b * LL + c * CL;

  // cooperative stage: B panel (rows t0..t0+63, cols DR..DR+15)
  {
    int row = tid >> 2, col0 = (tid & 3) * 4;
    *(float4v*)&lds_b[row * DS + col0] =
        *(const float4v*)&xdbl[(size_t)(t0 + row) * 96 + DR + col0];
  }

  float Aj2[DS];
  const float4v* Ap = (const float4v*)&A_log[d * DS];
#pragma unroll
  for (int i = 0; i < 4; ++i) {
    float4v v = Ap[i];
#pragma unroll
    for (int j = 0; j < 4; ++j) Aj2[i * 4 + j] = -__expf(v[j]) * LOG2E;
  }

  float h[DS];
#pragma unroll
  for (int s = 0; s < DS; ++s) h[s] = 0.f;
  float sd = 0.f;

  const bf16* dp = delta + (size_t)t0 * DI + d;
  const bf16* up = u + (size_t)t0 * DI + d;
  __syncthreads();

  for (int i = 0; i < CL; ++i) {
    float dlt = cvt(*dp); dp += DI;
    float ut = cvt(*up); up += DI;
    float Bv[DS];
    const float4v* Bp = (const float4v*)&lds_b[i * DS];
#pragma unroll
    for (int q = 0; q < 4; ++q) {
      float4v v = Bp[q];
#pragma unroll
      for (int j = 0; j < 4; ++j) Bv[q * 4 + j] = v[j];
    }
    float du = dlt * ut;
    sd += dlt;
#pragma unroll
    for (int s = 0; s < DS; ++s)
      h[s] = fmaf(exp2f(dlt * Aj2[s]), h[s], du * Bv[s]);
  }

  float4v* hv = (float4v*)stslot(xz, (chain * NC + c) * DS);
#pragma unroll
  for (int q = 0; q < 4; ++q) {
    float4v v;
#pragma unroll
    for (int j = 0; j < 4; ++j) v[j] = h[q * 4 + j];
    hv[q] = v;
  }
  *stslot(xz, SUMD_BASE + chain * NC + c) = sd;
}

__global__ __launch_bounds__(256) void scan_fix(
    bf16* __restrict__ xz, const float* __restrict__ A_log) {
  int lane = threadIdx.x & 15;
  int chain = blockIdx.x * 16 + (threadIdx.x >> 4);
  int d = chain & (DI - 1);
  float Aj = -__expf(A_log[d * DS + lane]);
  float carry = 0.f;
  for (int c = 0; c < NC; ++c) {
    float* hp = stslot(xz, (chain * NC + c) * DS + lane);
    float sd = *stslot(xz, SUMD_BASE + chain * NC + c);
    float he = *hp;
    *hp = carry;
    carry = fmaf(__expf(Aj * sd), carry, he);
  }
}

__global__ __launch_bounds__(256) void scan_final(
    const bf16* __restrict__ delta, bf16* __restrict__ u,
    const float* __restrict__ xdbl, bf16* __restrict__ xz,
    const float* __restrict__ A_log, const float* __restrict__ Dp) {
  __shared__ float lds_bc[CL * 2 * DS];   // 64 x 32 f32 = 8 KB
  int tid = threadIdx.x;
  int g = blockIdx.x * 256 + tid;
  int d = g & (DI - 1);
  int b = (g >> 11) & (BB - 1);
  int c = g >> 13;
  int chain = (b << 11) | d;
  int t0 = b * LL + c * CL;

  // cooperative stage: B+C panel (rows t0..t0+63, cols DR..DR+31)
  {
    int row = tid >> 2, col0 = (tid & 3) * 8;
    const float4v* src = (const float4v*)&xdbl[(size_t)(t0 + row) * 96 + DR + col0];
    *(float4v*)&lds_bc[row * 32 + col0] = src[0];
    *(float4v*)&lds_bc[row * 32 + col0 + 4] = src[1];
  }

  float Aj2[DS];
  const float4v* Ap = (const float4v*)&A_log[d * DS];
#pragma unroll
  for (int i = 0; i < 4; ++i) {
    float4v v = Ap[i];
#pragma unroll
    for (int j = 0; j < 4; ++j) Aj2[i * 4 + j] = -__expf(v[j]) * LOG2E;
  }
  float Dd = Dp[d];

  float h[DS];
  const float4v* hv = (const float4v*)stslot(xz, (chain * NC + c) * DS);
#pragma unroll
  for (int q = 0; q < 4; ++q) {
    float4v v = hv[q];
#pragma unroll
    for (int j = 0; j < 4; ++j) h[q * 4 + j] = v[j];
  }

  const bf16* dp = delta + (size_t)t0 * DI + d;
  bf16* uw = u + (size_t)t0 * DI + d;
  const bf16* zp = xz + (size_t)t0 * (2 * DI) + DI + d;
  __syncthreads();

  for (int i = 0; i < CL; ++i) {
    float dlt = cvt(*dp); dp += DI;
    float ut = cvt(*uw);
    float zt = cvt(*zp); zp += 2 * DI;
    float BC[2 * DS];
    const float4v* Bp = (const float4v*)&lds_bc[i * 32];
#pragma unroll
    for (int q = 0; q < 8; ++q) {
      float4v v = Bp[q];
#pragma unroll
      for (int j = 0; j < 4; ++j) BC[q * 4 + j] = v[j];
    }
    float du = dlt * ut;
    float yp = 0.f;
#pragma unroll
    for (int s = 0; s < DS; ++s) {
      h[s] = fmaf(exp2f(dlt * Aj2[s]), h[s], du * BC[s]);
      yp = fmaf(h[s], BC[DS + s], yp);
    }
    float gte = zt / (1.f + __expf(-zt));
    stv(uw, (yp + ut * Dd) * gte);
    uw += DI;
  }
}

// ---------------------------------------------------------------------------
extern "C" void kernel_launch(void* const* d_in, const int* in_sizes, int n_in,
                              void* d_out, int out_size, void* d_ws, size_t ws_size,
                              hipStream_t stream) {
  const float* hidden    = (const float*)d_in[0];
  const float* in_proj_w = (const float*)d_in[1];
  const float* conv_w    = (const float*)d_in[2];
  const float* conv_b    = (const float*)d_in[3];
  const float* x_proj_w  = (const float*)d_in[4];
  const float* dt_proj_w = (const float*)d_in[5];
  const float* dt_proj_b = (const float*)d_in[6];
  const float* A_log     = (const float*)d_in[7];
  const float* D_param   = (const float*)d_in[8];
  const float* out_proj_w= (const float*)d_in[9];
  float* out = (float*)d_out;

  // Workspace (131 MB, proven):
  //   xz 64MB bf16 | u 32MB bf16 | xdbl 3MB f32 | delta 32MB bf16
  size_t need = (size_t)TT * 4096 * sizeof(bf16) + (size_t)TT * DI * sizeof(bf16)
              + (size_t)TT * (DR + 2 * DS) * sizeof(float) + (size_t)TT * DI * sizeof(bf16);
  if (ws_size < need) return;

  bf16* xz     = (bf16*)d_ws;
  bf16* u      = xz + (size_t)TT * 2 * DI;
  float* xdbl  = (float*)(u + (size_t)TT * DI);
  bf16* delta  = (bf16*)(xdbl + (size_t)TT * (DR + 2 * DS));

  bf16* hbf   = u;                         // 8192x1024 bf16 (16MB)
  bf16* wbf   = u + (size_t)TT * DM;       // 4096x1024 bf16 (8MB)
  bf16* wx_bf = delta;                     // 96x2048 bf16, dead at step 4
  bf16* opbf  = delta;                     // 1024x2048 bf16, written at 5b

  dim3 blk(256);

  // 0) pre-convert inputs/weights to bf16
  cvt_bf16<<<dim3(TT * DM / 8 / 256), blk, 0, stream>>>(hidden, hbf, TT * DM / 8);
  cvt_bf16<<<dim3(2 * DI * DM / 8 / 256), blk, 0, stream>>>(in_proj_w, wbf, 2 * DI * DM / 8);
  cvt_bf16<<<dim3(96 * DI / 8 / 256), blk, 0, stream>>>(x_proj_w, wx_bf, 96 * DI / 8);

  // 1) xz = hidden @ in_proj_w^T   (dbuf bf16 GEMM)
  gemm_bf16<bf16><<<dim3(4096 / 128, TT / 128), blk, 0, stream>>>(
      hbf, DM, wbf, DM, xz, 2 * DI, DM);

  // 2) u = silu(causal_conv(x) + cb)
  conv_silu<<<dim3(TT), blk, 0, stream>>>(xz, conv_w, conv_b, u);

  // 3) x_dbl = u @ x_proj_w^T      (MFMA split-K)
  xproj_splitk<<<dim3(TT / 128, SK), blk, 0, stream>>>(u, wx_bf, xz);
  xproj_reduce<<<dim3(TT * 96 / 256), blk, 0, stream>>>(xz, xdbl);

  // 4) delta = softplus(x_dbl[:, :64] @ dt_proj_w^T + b)
  gemm_mfma<float, bf16, 1><<<dim3(DI / 128, TT / 128), blk, 0, stream>>>(
      xdbl, DR + 2 * DS, dt_proj_w, DR, dt_proj_b, delta, DI, DR);

  // 5) chunked selective scan; y -> in-place into u
  scan_local<<<dim3(8192 * NC / 256), blk, 0, stream>>>(delta, u, xdbl, xz, A_log);
  scan_fix<<<dim3(8192 / 16), blk, 0, stream>>>(xz, A_log);
  scan_final<<<dim3(8192 * NC / 256), blk, 0, stream>>>(delta, u, xdbl, xz, A_log, D_param);

  // 5b) convert out_proj_w -> bf16
  cvt_bf16<<<dim3(DM * DI / 8 / 256), blk, 0, stream>>>(out_proj_w, opbf, DM * DI / 8);

  // 6) out = y @ out_proj_w^T      (dbuf bf16 GEMM)
  gemm_bf16<float><<<dim3(DM / 128, TT / 128), blk, 0, stream>>>(
      u, DI, opbf, DI, out, DM, DI);
}

// Round 10
// 566.435 us; speedup vs baseline: 1.0056x; 1.0056x over previous
//
#include <hip/hip_runtime.h>
#include <hip/hip_bf16.h>
#include <math.h>

// Problem constants
#define BB 4
#define LL 2048
#define DM 1024
#define DI 2048
#define DS 16
#define DR 64
#define KC 4
#define TT (BB * LL)   // 8192 tokens
#define NC 64          // scan chunks per sequence
#define CL (LL / NC)   // 32 steps per chunk
#define SK 8           // x_proj split-K factor
#define LOG2E 1.4426950408889634f

typedef __hip_bfloat16 bf16;
typedef short bf16x8 __attribute__((ext_vector_type(8)));
typedef short short8 __attribute__((ext_vector_type(8)));
typedef float f32x4 __attribute__((ext_vector_type(4)));
typedef float float4v __attribute__((ext_vector_type(4)));

__device__ __forceinline__ float cvt(float v) { return v; }
__device__ __forceinline__ float cvt(bf16 v) { return __bfloat162float(v); }
__device__ __forceinline__ float bf2f(short s) {
  union { short s; bf16 h; } c; c.s = s; return __bfloat162float(c.h);
}
__device__ __forceinline__ void stv(float* p, float v) { *p = v; }
__device__ __forceinline__ void stv(bf16* p, float v) { *p = __float2bfloat16(v); }
__device__ __forceinline__ short f2bf(float f) {
  union { bf16 h; short s; } u_; u_.h = __float2bfloat16(f); return u_.s;
}

// async global->LDS, 16B per lane; lds dest must be WAVE-UNIFORM base (HW adds lane*16)
__device__ __forceinline__ void gld16(const bf16* g, bf16* l) {
  __builtin_amdgcn_global_load_lds(
      (const __attribute__((address_space(1))) void*)g,
      (__attribute__((address_space(3))) void*)l, 16, 0, 0);
}

// ---------------------------------------------------------------------------
// f32 -> bf16 bulk convert (8 elems/thread, n8 = n/8)
// ---------------------------------------------------------------------------
__global__ __launch_bounds__(256) void cvt_bf16(
    const float* __restrict__ src, bf16* __restrict__ dst, int n8) {
  int i = blockIdx.x * 256 + threadIdx.x;
  if (i >= n8) return;
  const float4v* s = (const float4v*)(src + (size_t)i * 8);
  float4v v0 = s[0], v1 = s[1];
  short8 o;
#pragma unroll
  for (int j = 0; j < 4; ++j) { o[j] = f2bf(v0[j]); o[4 + j] = f2bf(v1[j]); }
  *(short8*)(dst + (size_t)i * 8) = o;
}

// ---------------------------------------------------------------------------
// Pure-bf16 MFMA GEMM, 2-phase double-buffered (unchanged).
// ---------------------------------------------------------------------------
template <typename TC>
__global__ __launch_bounds__(256) void gemm_bf16(
    const bf16* __restrict__ A, int lda,
    const bf16* __restrict__ W, int ldw,
    TC* __restrict__ C, int ldc, int Kd) {
  __shared__ bf16 As[2][128 * 32];
  __shared__ bf16 Bs[2][128 * 32];
  int tid = threadIdx.x;
  int bm = blockIdx.y * 128, bn = blockIdx.x * 128;
  int wave = tid >> 6, lane = tid & 63;
  int wm = (wave >> 1) * 64, wn = (wave & 1) * 64;
  int lr = lane & 15, kg = lane >> 4;

  int srow = wave * 16 + (lane >> 2);
  int kc = (lane & 3) * 8;
  const bf16* gA0 = A + (size_t)(bm + srow) * lda + kc;
  const bf16* gA1 = gA0 + (size_t)64 * lda;
  const bf16* gW0 = W + (size_t)(bn + srow) * ldw + kc;
  const bf16* gW1 = gW0 + (size_t)64 * ldw;

  f32x4 acc[4][4] = {};

#define STAGE_BF(p, k0)                              \
  do {                                               \
    gld16(gA0 + (k0), &As[p][wave * 512]);           \
    gld16(gA1 + (k0), &As[p][2048 + wave * 512]);    \
    gld16(gW0 + (k0), &Bs[p][wave * 512]);           \
    gld16(gW1 + (k0), &Bs[p][2048 + wave * 512]);    \
  } while (0)

#define COMPUTE_BF(p)                                                         \
  do {                                                                        \
    bf16x8 af[4], bfr[4];                                                     \
    _Pragma("unroll") for (int i = 0; i < 4; ++i)                             \
        af[i] = *(const bf16x8*)&As[p][(wm + i * 16 + lr) * 32 + kg * 8];     \
    _Pragma("unroll") for (int j = 0; j < 4; ++j)                             \
        bfr[j] = *(const bf16x8*)&Bs[p][(wn + j * 16 + lr) * 32 + kg * 8];    \
    _Pragma("unroll") for (int i = 0; i < 4; ++i)                             \
        _Pragma("unroll") for (int j = 0; j < 4; ++j)                         \
            acc[i][j] = __builtin_amdgcn_mfma_f32_16x16x32_bf16(              \
                af[i], bfr[j], acc[i][j], 0, 0, 0);                           \
  } while (0)

  STAGE_BF(0, 0);
  __syncthreads();
  int p = 0;
  for (int k0 = 0; k0 < Kd - 32; k0 += 32) {
    STAGE_BF(p ^ 1, k0 + 32);
    COMPUTE_BF(p);
    __syncthreads();
    p ^= 1;
  }
  COMPUTE_BF(p);

#pragma unroll
  for (int i = 0; i < 4; ++i) {
    int row0 = bm + wm + i * 16 + kg * 4;
#pragma unroll
    for (int j = 0; j < 4; ++j) {
      int col = bn + wn + j * 16 + lr;
#pragma unroll
      for (int rr = 0; rr < 4; ++rr)
        stv(&C[(size_t)(row0 + rr) * ldc + col], acc[i][j][rr]);
    }
  }
#undef STAGE_BF
#undef COMPUTE_BF
}

// ---------------------------------------------------------------------------
// Reg-staged MFMA GEMM with f32->bf16 convert (dt_proj) + bias+softplus epi.
// ---------------------------------------------------------------------------
__device__ __forceinline__ void loadcvt16(const float* p, short* d) {
#pragma unroll
  for (int i = 0; i < 4; ++i) {
    float4v v = ((const float4v*)p)[i];
#pragma unroll
    for (int j = 0; j < 4; ++j) d[i * 4 + j] = f2bf(v[j]);
  }
}
__device__ __forceinline__ void loadcvt16(const bf16* p, short* d) {
  ((short8*)d)[0] = ((const short8*)p)[0];
  ((short8*)d)[1] = ((const short8*)p)[1];
}

template <typename TA, typename TC, int EPI>
__global__ __launch_bounds__(256) void gemm_mfma(
    const TA* __restrict__ A, int lda,
    const float* __restrict__ W, int ldw,
    const float* __restrict__ bias,
    TC* __restrict__ C, int ldc, int Kd) {
  __shared__ short As[128 * 40];
  __shared__ short Bs[128 * 40];
  int tid = threadIdx.x;
  int bm = blockIdx.y * 128, bn = blockIdx.x * 128;

  int r = tid >> 1, hh = (tid & 1) * 16;
  const TA* ga = A + (size_t)(bm + r) * lda + hh;
  const float* gw = W + (size_t)(bn + r) * ldw + hh;

  int wave = tid >> 6, lane = tid & 63;
  int wm = (wave >> 1) * 64, wn = (wave & 1) * 64;
  int lr = lane & 15, kg = lane >> 4;

  f32x4 acc[4][4] = {};

  for (int k0 = 0; k0 < Kd; k0 += 32) {
    short abuf[16], wbuf[16];
    loadcvt16(ga + k0, abuf);
    loadcvt16(gw + k0, wbuf);
    __syncthreads();
    ((short8*)&As[r * 40 + hh])[0] = ((short8*)abuf)[0];
    ((short8*)&As[r * 40 + hh])[1] = ((short8*)abuf)[1];
    ((short8*)&Bs[r * 40 + hh])[0] = ((short8*)wbuf)[0];
    ((short8*)&Bs[r * 40 + hh])[1] = ((short8*)wbuf)[1];
    __syncthreads();

    bf16x8 af[4], bfr[4];
#pragma unroll
    for (int i = 0; i < 4; ++i)
      af[i] = *(const bf16x8*)&As[(wm + i * 16 + lr) * 40 + kg * 8];
#pragma unroll
    for (int j = 0; j < 4; ++j)
      bfr[j] = *(const bf16x8*)&Bs[(wn + j * 16 + lr) * 40 + kg * 8];
#pragma unroll
    for (int i = 0; i < 4; ++i)
#pragma unroll
      for (int j = 0; j < 4; ++j)
        acc[i][j] = __builtin_amdgcn_mfma_f32_16x16x32_bf16(af[i], bfr[j], acc[i][j], 0, 0, 0);
  }

#pragma unroll
  for (int i = 0; i < 4; ++i) {
    int row0 = bm + wm + i * 16 + kg * 4;
#pragma unroll
    for (int j = 0; j < 4; ++j) {
      int col = bn + wn + j * 16 + lr;
#pragma unroll
      for (int rr = 0; rr < 4; ++rr) {
        float v = acc[i][j][rr];
        if (EPI == 1) {
          v += bias[col];
          v = (v > 20.f) ? v : log1pf(expf(v));
        }
        stv(&C[(size_t)(row0 + rr) * ldc + col], v);
      }
    }
  }
}

// ---------------------------------------------------------------------------
// Scan-state aliasing:
//   hend/hin: x-half of xz rows (stslot idx < 8192*1024 floats). NC=64 fills
//             rows 0..8191 exactly.
//   sumd:     dt-columns (0..63) of xdbl, dead after dt_proj.
// ---------------------------------------------------------------------------
__device__ __forceinline__ float* stslot(bf16* xz, int idx) {
  int t = idx >> 10, j = idx & 1023;
  return (float*)((char*)xz + (size_t)t * 8192) + j;
}
__device__ __forceinline__ float* sumd_slot(float* xdbl, int i) {
  return &xdbl[(size_t)(i >> 6) * 96 + (i & 63)];
}

// ---------------------------------------------------------------------------
// x_proj split-K, bf16 weights (unchanged). Partials in dead x-half of xz.
// ---------------------------------------------------------------------------
__global__ __launch_bounds__(256) void xproj_splitk(
    const bf16* __restrict__ u, const bf16* __restrict__ W,
    bf16* __restrict__ xz) {
  __shared__ short As[128 * 40];
  __shared__ short Bs[96 * 40];
  int tid = threadIdx.x;
  int bm = blockIdx.x * 128;
  int sk = blockIdx.y;
  int kb = sk * (DI / SK);

  int r = tid >> 1, hh = (tid & 1) * 16;
  const bf16* ga = u + (size_t)(bm + r) * DI + kb + hh;
  const bf16* gw = W + (size_t)r * DI + kb + hh;

  int wave = tid >> 6, lane = tid & 63;
  int wm = wave * 32;
  int lr = lane & 15, kg = lane >> 4;

  f32x4 acc[2][6] = {};

  for (int k0 = 0; k0 < DI / SK; k0 += 32) {
    short abuf[16], wbuf[16];
    loadcvt16(ga + k0, abuf);
    if (r < 96) loadcvt16(gw + k0, wbuf);
    __syncthreads();
    ((short8*)&As[r * 40 + hh])[0] = ((short8*)abuf)[0];
    ((short8*)&As[r * 40 + hh])[1] = ((short8*)abuf)[1];
    if (r < 96) {
      ((short8*)&Bs[r * 40 + hh])[0] = ((short8*)wbuf)[0];
      ((short8*)&Bs[r * 40 + hh])[1] = ((short8*)wbuf)[1];
    }
    __syncthreads();

    bf16x8 af[2], bfr[6];
#pragma unroll
    for (int i = 0; i < 2; ++i)
      af[i] = *(const bf16x8*)&As[(wm + i * 16 + lr) * 40 + kg * 8];
#pragma unroll
    for (int j = 0; j < 6; ++j)
      bfr[j] = *(const bf16x8*)&Bs[(j * 16 + lr) * 40 + kg * 8];
#pragma unroll
    for (int i = 0; i < 2; ++i)
#pragma unroll
      for (int j = 0; j < 6; ++j)
        acc[i][j] = __builtin_amdgcn_mfma_f32_16x16x32_bf16(af[i], bfr[j], acc[i][j], 0, 0, 0);
  }

#pragma unroll
  for (int i = 0; i < 2; ++i) {
#pragma unroll
    for (int j = 0; j < 6; ++j) {
      int col = j * 16 + lr;
#pragma unroll
      for (int rr = 0; rr < 4; ++rr) {
        int row = bm + wm + i * 16 + kg * 4 + rr;
        *stslot(xz, (sk * 8192 + row) * 96 + col) = acc[i][j][rr];
      }
    }
  }
}

__global__ __launch_bounds__(256) void xproj_reduce(
    bf16* __restrict__ xz, float* __restrict__ xdbl) {
  int gid = blockIdx.x * 256 + threadIdx.x;
  float s = 0.f;
#pragma unroll
  for (int sk = 0; sk < SK; ++sk)
    s += *stslot(xz, sk * (8192 * 96) + gid);
  xdbl[gid] = s;
}

// ---------------------------------------------------------------------------
// Depthwise causal conv1d (K=4) + bias + SiLU — vectorized (unchanged).
// ---------------------------------------------------------------------------
__global__ __launch_bounds__(256) void conv_silu(
    const bf16* __restrict__ xz, const float* __restrict__ cw,
    const float* __restrict__ cb, bf16* __restrict__ u) {
  int t = blockIdx.x;
  int d0 = threadIdx.x * 8;
  int l = t & (LL - 1);

  float acc[8];
  float4v c0 = *(const float4v*)&cb[d0];
  float4v c1 = *(const float4v*)&cb[d0 + 4];
#pragma unroll
  for (int j = 0; j < 4; ++j) { acc[j] = c0[j]; acc[4 + j] = c1[j]; }

  float wv[32];
  const float4v* wp = (const float4v*)&cw[d0 * 4];
#pragma unroll
  for (int q = 0; q < 8; ++q) {
    float4v v = wp[q];
#pragma unroll
    for (int j = 0; j < 4; ++j) wv[q * 4 + j] = v[j];
  }

#pragma unroll
  for (int k = 0; k < KC; ++k) {
    int lt = l - (KC - 1) + k;
    if (lt >= 0) {
      short8 xv = *(const short8*)&xz[(size_t)(t - (KC - 1) + k) * (2 * DI) + d0];
#pragma unroll
      for (int q = 0; q < 8; ++q)
        acc[q] = fmaf(bf2f(xv[q]), wv[q * 4 + k], acc[q]);
    }
  }

  short8 ov;
#pragma unroll
  for (int q = 0; q < 8; ++q) {
    float s = acc[q] / (1.f + __expf(-acc[q]));
    ov[q] = f2bf(s);
  }
  *(short8*)&u[(size_t)t * DI + d0] = ov;
}

// ---------------------------------------------------------------------------
// Chunked selective scan, thread-per-chain, NC=64 for occupancy, LDS-staged
// B/C panels, exp2 prescaled A, unrolled loops for load prefetch.
// Block = 256 consecutive d's, same (b,c) -> shared B/C panel.
// ---------------------------------------------------------------------------
__global__ __launch_bounds__(256) void scan_local(
    const bf16* __restrict__ delta, const bf16* __restrict__ u,
    float* __restrict__ xdbl, bf16* __restrict__ xz,
    const float* __restrict__ A_log) {
  __shared__ float lds_b[CL * DS];   // 32 x 16 f32 = 2 KB
  int tid = threadIdx.x;
  int g = blockIdx.x * 256 + tid;
  int d = g & (DI - 1);
  int b = (g >> 11) & (BB - 1);
  int c = g >> 13;
  int chain = (b << 11) | d;
  int t0 = b * LL + c * CL;

  if (tid < CL * 4) {
    int row = tid >> 2, col0 = (tid & 3) * 4;
    *(float4v*)&lds_b[row * DS + col0] =
        *(const float4v*)&xdbl[(size_t)(t0 + row) * 96 + DR + col0];
  }

  float Aj2[DS];
  const float4v* Ap = (const float4v*)&A_log[d * DS];
#pragma unroll
  for (int i = 0; i < 4; ++i) {
    float4v v = Ap[i];
#pragma unroll
    for (int j = 0; j < 4; ++j) Aj2[i * 4 + j] = -__expf(v[j]) * LOG2E;
  }

  float h[DS];
#pragma unroll
  for (int s = 0; s < DS; ++s) h[s] = 0.f;
  float sd = 0.f;

  const bf16* dp = delta + (size_t)t0 * DI + d;
  const bf16* up = u + (size_t)t0 * DI + d;
  __syncthreads();

#pragma unroll 2
  for (int i = 0; i < CL; ++i) {
    float dlt = cvt(*dp); dp += DI;
    float ut = cvt(*up); up += DI;
    const float4v* Bp = (const float4v*)&lds_b[i * DS];
    float4v bq0 = Bp[0], bq1 = Bp[1], bq2 = Bp[2], bq3 = Bp[3];
    float du = dlt * ut;
    sd += dlt;
#pragma unroll
    for (int j = 0; j < 4; ++j) {
      h[j]      = fmaf(exp2f(dlt * Aj2[j]),      h[j],      du * bq0[j]);
      h[4 + j]  = fmaf(exp2f(dlt * Aj2[4 + j]),  h[4 + j],  du * bq1[j]);
      h[8 + j]  = fmaf(exp2f(dlt * Aj2[8 + j]),  h[8 + j],  du * bq2[j]);
      h[12 + j] = fmaf(exp2f(dlt * Aj2[12 + j]), h[12 + j], du * bq3[j]);
    }
  }

  float4v* hv = (float4v*)stslot(xz, (chain * NC + c) * DS);
#pragma unroll
  for (int q = 0; q < 4; ++q) {
    float4v v;
#pragma unroll
    for (int j = 0; j < 4; ++j) v[j] = h[q * 4 + j];
    hv[q] = v;
  }
  *sumd_slot(xdbl, chain * NC + c) = sd;
}

__global__ __launch_bounds__(256) void scan_fix(
    bf16* __restrict__ xz, const float* __restrict__ xdbl,
    const float* __restrict__ A_log) {
  int lane = threadIdx.x & 15;
  int chain = blockIdx.x * 16 + (threadIdx.x >> 4);
  int d = chain & (DI - 1);
  float Aj2 = -__expf(A_log[d * DS + lane]) * LOG2E;
  float carry = 0.f;
#pragma unroll 4
  for (int c = 0; c < NC; ++c) {
    float* hp = stslot(xz, (chain * NC + c) * DS + lane);
    float sd = *sumd_slot((float*)xdbl, chain * NC + c);
    float he = *hp;
    *hp = carry;
    carry = fmaf(exp2f(Aj2 * sd), carry, he);
  }
}

__global__ __launch_bounds__(256) void scan_final(
    const bf16* __restrict__ delta, bf16* __restrict__ u,
    const float* __restrict__ xdbl, bf16* __restrict__ xz,
    const float* __restrict__ A_log, const float* __restrict__ Dp) {
  __shared__ float lds_bc[CL * 2 * DS];   // 32 x 32 f32 = 4 KB
  int tid = threadIdx.x;
  int g = blockIdx.x * 256 + tid;
  int d = g & (DI - 1);
  int b = (g >> 11) & (BB - 1);
  int c = g >> 13;
  int chain = (b << 11) | d;
  int t0 = b * LL + c * CL;

  if (tid < CL * 4) {
    int row = tid >> 2, col0 = (tid & 3) * 8;
    const float4v* src = (const float4v*)&xdbl[(size_t)(t0 + row) * 96 + DR + col0];
    *(float4v*)&lds_bc[row * 32 + col0] = src[0];
    *(float4v*)&lds_bc[row * 32 + col0 + 4] = src[1];
  }

  float Aj2[DS];
  const float4v* Ap = (const float4v*)&A_log[d * DS];
#pragma unroll
  for (int i = 0; i < 4; ++i) {
    float4v v = Ap[i];
#pragma unroll
    for (int j = 0; j < 4; ++j) Aj2[i * 4 + j] = -__expf(v[j]) * LOG2E;
  }
  float Dd = Dp[d];

  float h[DS];
  const float4v* hv = (const float4v*)stslot(xz, (chain * NC + c) * DS);
#pragma unroll
  for (int q = 0; q < 4; ++q) {
    float4v v = hv[q];
#pragma unroll
    for (int j = 0; j < 4; ++j) h[q * 4 + j] = v[j];
  }

  const bf16* dp = delta + (size_t)t0 * DI + d;
  bf16* uw = u + (size_t)t0 * DI + d;
  const bf16* zp = xz + (size_t)t0 * (2 * DI) + DI + d;
  __syncthreads();

#pragma unroll 2
  for (int i = 0; i < CL; ++i) {
    float dlt = cvt(*dp); dp += DI;
    float ut = cvt(*uw);
    float zt = cvt(*zp); zp += 2 * DI;
    const float4v* Bp = (const float4v*)&lds_bc[i * 32];
    float4v b0 = Bp[0], b1 = Bp[1], b2 = Bp[2], b3 = Bp[3];
    float4v c0 = Bp[4], c1 = Bp[5], c2 = Bp[6], c3 = Bp[7];
    float du = dlt * ut;
    float yp = 0.f;
#pragma unroll
    for (int j = 0; j < 4; ++j) {
      h[j]      = fmaf(exp2f(dlt * Aj2[j]),      h[j],      du * b0[j]);
      h[4 + j]  = fmaf(exp2f(dlt * Aj2[4 + j]),  h[4 + j],  du * b1[j]);
      h[8 + j]  = fmaf(exp2f(dlt * Aj2[8 + j]),  h[8 + j],  du * b2[j]);
      h[12 + j] = fmaf(exp2f(dlt * Aj2[12 + j]), h[12 + j], du * b3[j]);
      yp = fmaf(h[j], c0[j], yp);
      yp = fmaf(h[4 + j], c1[j], yp);
      yp = fmaf(h[8 + j], c2[j], yp);
      yp = fmaf(h[12 + j], c3[j], yp);
    }
    float gte = zt / (1.f + __expf(-zt));
    stv(uw, (yp + ut * Dd) * gte);
    uw += DI;
  }
}

// ---------------------------------------------------------------------------
extern "C" void kernel_launch(void* const* d_in, const int* in_sizes, int n_in,
                              void* d_out, int out_size, void* d_ws, size_t ws_size,
                              hipStream_t stream) {
  const float* hidden    = (const float*)d_in[0];
  const float* in_proj_w = (const float*)d_in[1];
  const float* conv_w    = (const float*)d_in[2];
  const float* conv_b    = (const float*)d_in[3];
  const float* x_proj_w  = (const float*)d_in[4];
  const float* dt_proj_w = (const float*)d_in[5];
  const float* dt_proj_b = (const float*)d_in[6];
  const float* A_log     = (const float*)d_in[7];
  const float* D_param   = (const float*)d_in[8];
  const float* out_proj_w= (const float*)d_in[9];
  float* out = (float*)d_out;

  // Workspace (131 MB, proven):
  //   xz 64MB bf16 | u 32MB bf16 | xdbl 3MB f32 | delta 32MB bf16
  size_t need = (size_t)TT * 4096 * sizeof(bf16) + (size_t)TT * DI * sizeof(bf16)
              + (size_t)TT * (DR + 2 * DS) * sizeof(float) + (size_t)TT * DI * sizeof(bf16);
  if (ws_size < need) return;

  bf16* xz     = (bf16*)d_ws;
  bf16* u      = xz + (size_t)TT * 2 * DI;
  float* xdbl  = (float*)(u + (size_t)TT * DI);
  bf16* delta  = (bf16*)(xdbl + (size_t)TT * (DR + 2 * DS));

  bf16* hbf   = u;                         // 8192x1024 bf16 (16MB)
  bf16* wbf   = u + (size_t)TT * DM;       // 4096x1024 bf16 (8MB)
  bf16* wx_bf = delta;                     // 96x2048 bf16, dead at step 4
  bf16* opbf  = delta;                     // 1024x2048 bf16, written at 5b

  dim3 blk(256);

  // 0) pre-convert inputs/weights to bf16
  cvt_bf16<<<dim3(TT * DM / 8 / 256), blk, 0, stream>>>(hidden, hbf, TT * DM / 8);
  cvt_bf16<<<dim3(2 * DI * DM / 8 / 256), blk, 0, stream>>>(in_proj_w, wbf, 2 * DI * DM / 8);
  cvt_bf16<<<dim3(96 * DI / 8 / 256), blk, 0, stream>>>(x_proj_w, wx_bf, 96 * DI / 8);

  // 1) xz = hidden @ in_proj_w^T   (dbuf bf16 GEMM)
  gemm_bf16<bf16><<<dim3(4096 / 128, TT / 128), blk, 0, stream>>>(
      hbf, DM, wbf, DM, xz, 2 * DI, DM);

  // 2) u = silu(causal_conv(x) + cb)
  conv_silu<<<dim3(TT), blk, 0, stream>>>(xz, conv_w, conv_b, u);

  // 3) x_dbl = u @ x_proj_w^T      (MFMA split-K)
  xproj_splitk<<<dim3(TT / 128, SK), blk, 0, stream>>>(u, wx_bf, xz);
  xproj_reduce<<<dim3(TT * 96 / 256), blk, 0, stream>>>(xz, xdbl);

  // 4) delta = softplus(x_dbl[:, :64] @ dt_proj_w^T + b)
  gemm_mfma<float, bf16, 1><<<dim3(DI / 128, TT / 128), blk, 0, stream>>>(
      xdbl, DR + 2 * DS, dt_proj_w, DR, dt_proj_b, delta, DI, DR);

  // 5) chunked selective scan (NC=64); y -> in-place into u
  scan_local<<<dim3(8192 * NC / 256), blk, 0, stream>>>(delta, u, xdbl, xz, A_log);
  scan_fix<<<dim3(8192 / 16), blk, 0, stream>>>(xz, xdbl, A_log);
  scan_final<<<dim3(8192 * NC / 256), blk, 0, stream>>>(delta, u, xdbl, xz, A_log, D_param);

  // 5b) convert out_proj_w -> bf16
  cvt_bf16<<<dim3(DM * DI / 8 / 256), blk, 0, stream>>>(out_proj_w, opbf, DM * DI / 8);

  // 6) out = y @ out_proj_w^T      (dbuf bf16 GEMM)
  gemm_bf16<float><<<dim3(DM / 128, TT / 128), blk, 0, stream>>>(
      u, DI, opbf, DI, out, DM, DI);
}

// Round 11
// 502.474 us; speedup vs baseline: 1.1336x; 1.1273x over previous
//
#include <hip/hip_runtime.h>
#include <hip/hip_bf16.h>
#include <math.h>

// Problem constants
#define BB 4
#define LL 2048
#define DM 1024
#define DI 2048
#define DS 16
#define DR 64
#define KC 4
#define TT (BB * LL)   // 8192 tokens
#define NC 64          // scan chunks per sequence
#define CL (LL / NC)   // 32 steps per chunk
#define SK 8           // x_proj split-K factor
#define LOG2E 1.4426950408889634f

typedef __hip_bfloat16 bf16;
typedef short bf16x8 __attribute__((ext_vector_type(8)));
typedef short short8 __attribute__((ext_vector_type(8)));
typedef float f32x4 __attribute__((ext_vector_type(4)));
typedef float float4v __attribute__((ext_vector_type(4)));

__device__ __forceinline__ float cvt(float v) { return v; }
__device__ __forceinline__ float cvt(bf16 v) { return __bfloat162float(v); }
__device__ __forceinline__ float bf2f(short s) {
  union { short s; bf16 h; } c; c.s = s; return __bfloat162float(c.h);
}
__device__ __forceinline__ void stv(float* p, float v) { *p = v; }
__device__ __forceinline__ void stv(bf16* p, float v) { *p = __float2bfloat16(v); }
__device__ __forceinline__ short f2bf(float f) {
  union { bf16 h; short s; } u_; u_.h = __float2bfloat16(f); return u_.s;
}

// RAW v_exp_f32 (2^x). libm exp2f is an __ocml call with range handling
// (~8 inst); the builtin is 1 inst. Args here are finite -> identical results.
#if __has_builtin(__builtin_amdgcn_exp2f)
__device__ __forceinline__ float fexp2(float x) { return __builtin_amdgcn_exp2f(x); }
#else
__device__ __forceinline__ float fexp2(float x) { return exp2f(x); }
#endif

// async global->LDS, 16B per lane; lds dest must be WAVE-UNIFORM base (HW adds lane*16)
__device__ __forceinline__ void gld16(const bf16* g, bf16* l) {
  __builtin_amdgcn_global_load_lds(
      (const __attribute__((address_space(1))) void*)g,
      (__attribute__((address_space(3))) void*)l, 16, 0, 0);
}

// ---------------------------------------------------------------------------
// f32 -> bf16 bulk convert (8 elems/thread, n8 = n/8)
// ---------------------------------------------------------------------------
__global__ __launch_bounds__(256) void cvt_bf16(
    const float* __restrict__ src, bf16* __restrict__ dst, int n8) {
  int i = blockIdx.x * 256 + threadIdx.x;
  if (i >= n8) return;
  const float4v* s = (const float4v*)(src + (size_t)i * 8);
  float4v v0 = s[0], v1 = s[1];
  short8 o;
#pragma unroll
  for (int j = 0; j < 4; ++j) { o[j] = f2bf(v0[j]); o[4 + j] = f2bf(v1[j]); }
  *(short8*)(dst + (size_t)i * 8) = o;
}

// ---------------------------------------------------------------------------
// Pure-bf16 MFMA GEMM, 2-phase double-buffered (unchanged).
// ---------------------------------------------------------------------------
template <typename TC>
__global__ __launch_bounds__(256) void gemm_bf16(
    const bf16* __restrict__ A, int lda,
    const bf16* __restrict__ W, int ldw,
    TC* __restrict__ C, int ldc, int Kd) {
  __shared__ bf16 As[2][128 * 32];
  __shared__ bf16 Bs[2][128 * 32];
  int tid = threadIdx.x;
  int bm = blockIdx.y * 128, bn = blockIdx.x * 128;
  int wave = tid >> 6, lane = tid & 63;
  int wm = (wave >> 1) * 64, wn = (wave & 1) * 64;
  int lr = lane & 15, kg = lane >> 4;

  int srow = wave * 16 + (lane >> 2);
  int kc = (lane & 3) * 8;
  const bf16* gA0 = A + (size_t)(bm + srow) * lda + kc;
  const bf16* gA1 = gA0 + (size_t)64 * lda;
  const bf16* gW0 = W + (size_t)(bn + srow) * ldw + kc;
  const bf16* gW1 = gW0 + (size_t)64 * ldw;

  f32x4 acc[4][4] = {};

#define STAGE_BF(p, k0)                              \
  do {                                               \
    gld16(gA0 + (k0), &As[p][wave * 512]);           \
    gld16(gA1 + (k0), &As[p][2048 + wave * 512]);    \
    gld16(gW0 + (k0), &Bs[p][wave * 512]);           \
    gld16(gW1 + (k0), &Bs[p][2048 + wave * 512]);    \
  } while (0)

#define COMPUTE_BF(p)                                                         \
  do {                                                                        \
    bf16x8 af[4], bfr[4];                                                     \
    _Pragma("unroll") for (int i = 0; i < 4; ++i)                             \
        af[i] = *(const bf16x8*)&As[p][(wm + i * 16 + lr) * 32 + kg * 8];     \
    _Pragma("unroll") for (int j = 0; j < 4; ++j)                             \
        bfr[j] = *(const bf16x8*)&Bs[p][(wn + j * 16 + lr) * 32 + kg * 8];    \
    _Pragma("unroll") for (int i = 0; i < 4; ++i)                             \
        _Pragma("unroll") for (int j = 0; j < 4; ++j)                         \
            acc[i][j] = __builtin_amdgcn_mfma_f32_16x16x32_bf16(              \
                af[i], bfr[j], acc[i][j], 0, 0, 0);                           \
  } while (0)

  STAGE_BF(0, 0);
  __syncthreads();
  int p = 0;
  for (int k0 = 0; k0 < Kd - 32; k0 += 32) {
    STAGE_BF(p ^ 1, k0 + 32);
    COMPUTE_BF(p);
    __syncthreads();
    p ^= 1;
  }
  COMPUTE_BF(p);

#pragma unroll
  for (int i = 0; i < 4; ++i) {
    int row0 = bm + wm + i * 16 + kg * 4;
#pragma unroll
    for (int j = 0; j < 4; ++j) {
      int col = bn + wn + j * 16 + lr;
#pragma unroll
      for (int rr = 0; rr < 4; ++rr)
        stv(&C[(size_t)(row0 + rr) * ldc + col], acc[i][j][rr]);
    }
  }
#undef STAGE_BF
#undef COMPUTE_BF
}

// ---------------------------------------------------------------------------
// Reg-staged MFMA GEMM with f32->bf16 convert (dt_proj) + bias+softplus epi.
// ---------------------------------------------------------------------------
__device__ __forceinline__ void loadcvt16(const float* p, short* d) {
#pragma unroll
  for (int i = 0; i < 4; ++i) {
    float4v v = ((const float4v*)p)[i];
#pragma unroll
    for (int j = 0; j < 4; ++j) d[i * 4 + j] = f2bf(v[j]);
  }
}
__device__ __forceinline__ void loadcvt16(const bf16* p, short* d) {
  ((short8*)d)[0] = ((const short8*)p)[0];
  ((short8*)d)[1] = ((const short8*)p)[1];
}

template <typename TA, typename TC, int EPI>
__global__ __launch_bounds__(256) void gemm_mfma(
    const TA* __restrict__ A, int lda,
    const float* __restrict__ W, int ldw,
    const float* __restrict__ bias,
    TC* __restrict__ C, int ldc, int Kd) {
  __shared__ short As[128 * 40];
  __shared__ short Bs[128 * 40];
  int tid = threadIdx.x;
  int bm = blockIdx.y * 128, bn = blockIdx.x * 128;

  int r = tid >> 1, hh = (tid & 1) * 16;
  const TA* ga = A + (size_t)(bm + r) * lda + hh;
  const float* gw = W + (size_t)(bn + r) * ldw + hh;

  int wave = tid >> 6, lane = tid & 63;
  int wm = (wave >> 1) * 64, wn = (wave & 1) * 64;
  int lr = lane & 15, kg = lane >> 4;

  f32x4 acc[4][4] = {};

  for (int k0 = 0; k0 < Kd; k0 += 32) {
    short abuf[16], wbuf[16];
    loadcvt16(ga + k0, abuf);
    loadcvt16(gw + k0, wbuf);
    __syncthreads();
    ((short8*)&As[r * 40 + hh])[0] = ((short8*)abuf)[0];
    ((short8*)&As[r * 40 + hh])[1] = ((short8*)abuf)[1];
    ((short8*)&Bs[r * 40 + hh])[0] = ((short8*)wbuf)[0];
    ((short8*)&Bs[r * 40 + hh])[1] = ((short8*)wbuf)[1];
    __syncthreads();

    bf16x8 af[4], bfr[4];
#pragma unroll
    for (int i = 0; i < 4; ++i)
      af[i] = *(const bf16x8*)&As[(wm + i * 16 + lr) * 40 + kg * 8];
#pragma unroll
    for (int j = 0; j < 4; ++j)
      bfr[j] = *(const bf16x8*)&Bs[(wn + j * 16 + lr) * 40 + kg * 8];
#pragma unroll
    for (int i = 0; i < 4; ++i)
#pragma unroll
      for (int j = 0; j < 4; ++j)
        acc[i][j] = __builtin_amdgcn_mfma_f32_16x16x32_bf16(af[i], bfr[j], acc[i][j], 0, 0, 0);
  }

#pragma unroll
  for (int i = 0; i < 4; ++i) {
    int row0 = bm + wm + i * 16 + kg * 4;
#pragma unroll
    for (int j = 0; j < 4; ++j) {
      int col = bn + wn + j * 16 + lr;
#pragma unroll
      for (int rr = 0; rr < 4; ++rr) {
        float v = acc[i][j][rr];
        if (EPI == 1) {
          v += bias[col];
          v = (v > 20.f) ? v : log1pf(expf(v));
        }
        stv(&C[(size_t)(row0 + rr) * ldc + col], v);
      }
    }
  }
}

// ---------------------------------------------------------------------------
// Scan-state aliasing:
//   hend/hin: x-half of xz rows (stslot idx < 8192*1024 floats). NC=64 fills
//             rows 0..8191 exactly.
//   sumd:     dt-columns (0..63) of xdbl, dead after dt_proj.
// ---------------------------------------------------------------------------
__device__ __forceinline__ float* stslot(bf16* xz, int idx) {
  int t = idx >> 10, j = idx & 1023;
  return (float*)((char*)xz + (size_t)t * 8192) + j;
}
__device__ __forceinline__ float* sumd_slot(float* xdbl, int i) {
  return &xdbl[(size_t)(i >> 6) * 96 + (i & 63)];
}

// ---------------------------------------------------------------------------
// x_proj split-K, bf16 weights (unchanged). Partials in dead x-half of xz.
// ---------------------------------------------------------------------------
__global__ __launch_bounds__(256) void xproj_splitk(
    const bf16* __restrict__ u, const bf16* __restrict__ W,
    bf16* __restrict__ xz) {
  __shared__ short As[128 * 40];
  __shared__ short Bs[96 * 40];
  int tid = threadIdx.x;
  int bm = blockIdx.x * 128;
  int sk = blockIdx.y;
  int kb = sk * (DI / SK);

  int r = tid >> 1, hh = (tid & 1) * 16;
  const bf16* ga = u + (size_t)(bm + r) * DI + kb + hh;
  const bf16* gw = W + (size_t)r * DI + kb + hh;

  int wave = tid >> 6, lane = tid & 63;
  int wm = wave * 32;
  int lr = lane & 15, kg = lane >> 4;

  f32x4 acc[2][6] = {};

  for (int k0 = 0; k0 < DI / SK; k0 += 32) {
    short abuf[16], wbuf[16];
    loadcvt16(ga + k0, abuf);
    if (r < 96) loadcvt16(gw + k0, wbuf);
    __syncthreads();
    ((short8*)&As[r * 40 + hh])[0] = ((short8*)abuf)[0];
    ((short8*)&As[r * 40 + hh])[1] = ((short8*)abuf)[1];
    if (r < 96) {
      ((short8*)&Bs[r * 40 + hh])[0] = ((short8*)wbuf)[0];
      ((short8*)&Bs[r * 40 + hh])[1] = ((short8*)wbuf)[1];
    }
    __syncthreads();

    bf16x8 af[2], bfr[6];
#pragma unroll
    for (int i = 0; i < 2; ++i)
      af[i] = *(const bf16x8*)&As[(wm + i * 16 + lr) * 40 + kg * 8];
#pragma unroll
    for (int j = 0; j < 6; ++j)
      bfr[j] = *(const bf16x8*)&Bs[(j * 16 + lr) * 40 + kg * 8];
#pragma unroll
    for (int i = 0; i < 2; ++i)
#pragma unroll
      for (int j = 0; j < 6; ++j)
        acc[i][j] = __builtin_amdgcn_mfma_f32_16x16x32_bf16(af[i], bfr[j], acc[i][j], 0, 0, 0);
  }

#pragma unroll
  for (int i = 0; i < 2; ++i) {
#pragma unroll
    for (int j = 0; j < 6; ++j) {
      int col = j * 16 + lr;
#pragma unroll
      for (int rr = 0; rr < 4; ++rr) {
        int row = bm + wm + i * 16 + kg * 4 + rr;
        *stslot(xz, (sk * 8192 + row) * 96 + col) = acc[i][j][rr];
      }
    }
  }
}

__global__ __launch_bounds__(256) void xproj_reduce(
    bf16* __restrict__ xz, float* __restrict__ xdbl) {
  int gid = blockIdx.x * 256 + threadIdx.x;
  float s = 0.f;
#pragma unroll
  for (int sk = 0; sk < SK; ++sk)
    s += *stslot(xz, sk * (8192 * 96) + gid);
  xdbl[gid] = s;
}

// ---------------------------------------------------------------------------
// Depthwise causal conv1d (K=4) + bias + SiLU — vectorized (unchanged).
// ---------------------------------------------------------------------------
__global__ __launch_bounds__(256) void conv_silu(
    const bf16* __restrict__ xz, const float* __restrict__ cw,
    const float* __restrict__ cb, bf16* __restrict__ u) {
  int t = blockIdx.x;
  int d0 = threadIdx.x * 8;
  int l = t & (LL - 1);

  float acc[8];
  float4v c0 = *(const float4v*)&cb[d0];
  float4v c1 = *(const float4v*)&cb[d0 + 4];
#pragma unroll
  for (int j = 0; j < 4; ++j) { acc[j] = c0[j]; acc[4 + j] = c1[j]; }

  float wv[32];
  const float4v* wp = (const float4v*)&cw[d0 * 4];
#pragma unroll
  for (int q = 0; q < 8; ++q) {
    float4v v = wp[q];
#pragma unroll
    for (int j = 0; j < 4; ++j) wv[q * 4 + j] = v[j];
  }

#pragma unroll
  for (int k = 0; k < KC; ++k) {
    int lt = l - (KC - 1) + k;
    if (lt >= 0) {
      short8 xv = *(const short8*)&xz[(size_t)(t - (KC - 1) + k) * (2 * DI) + d0];
#pragma unroll
      for (int q = 0; q < 8; ++q)
        acc[q] = fmaf(bf2f(xv[q]), wv[q * 4 + k], acc[q]);
    }
  }

  short8 ov;
#pragma unroll
  for (int q = 0; q < 8; ++q) {
    float s = acc[q] / (1.f + __expf(-acc[q]));
    ov[q] = f2bf(s);
  }
  *(short8*)&u[(size_t)t * DI + d0] = ov;
}

// ---------------------------------------------------------------------------
// Chunked selective scan, thread-per-chain, NC=64, LDS-staged B/C panels,
// RAW v_exp_f32 via fexp2 (prescaled A), unrolled loops for load prefetch.
// ---------------------------------------------------------------------------
__global__ __launch_bounds__(256) void scan_local(
    const bf16* __restrict__ delta, const bf16* __restrict__ u,
    float* __restrict__ xdbl, bf16* __restrict__ xz,
    const float* __restrict__ A_log) {
  __shared__ float lds_b[CL * DS];   // 32 x 16 f32 = 2 KB
  int tid = threadIdx.x;
  int g = blockIdx.x * 256 + tid;
  int d = g & (DI - 1);
  int b = (g >> 11) & (BB - 1);
  int c = g >> 13;
  int chain = (b << 11) | d;
  int t0 = b * LL + c * CL;

  if (tid < CL * 4) {
    int row = tid >> 2, col0 = (tid & 3) * 4;
    *(float4v*)&lds_b[row * DS + col0] =
        *(const float4v*)&xdbl[(size_t)(t0 + row) * 96 + DR + col0];
  }

  float Aj2[DS];
  const float4v* Ap = (const float4v*)&A_log[d * DS];
#pragma unroll
  for (int i = 0; i < 4; ++i) {
    float4v v = Ap[i];
#pragma unroll
    for (int j = 0; j < 4; ++j) Aj2[i * 4 + j] = -__expf(v[j]) * LOG2E;
  }

  float h[DS];
#pragma unroll
  for (int s = 0; s < DS; ++s) h[s] = 0.f;
  float sd = 0.f;

  const bf16* dp = delta + (size_t)t0 * DI + d;
  const bf16* up = u + (size_t)t0 * DI + d;
  __syncthreads();

#pragma unroll 2
  for (int i = 0; i < CL; ++i) {
    float dlt = cvt(*dp); dp += DI;
    float ut = cvt(*up); up += DI;
    const float4v* Bp = (const float4v*)&lds_b[i * DS];
    float4v bq0 = Bp[0], bq1 = Bp[1], bq2 = Bp[2], bq3 = Bp[3];
    float du = dlt * ut;
    sd += dlt;
#pragma unroll
    for (int j = 0; j < 4; ++j) {
      h[j]      = fmaf(fexp2(dlt * Aj2[j]),      h[j],      du * bq0[j]);
      h[4 + j]  = fmaf(fexp2(dlt * Aj2[4 + j]),  h[4 + j],  du * bq1[j]);
      h[8 + j]  = fmaf(fexp2(dlt * Aj2[8 + j]),  h[8 + j],  du * bq2[j]);
      h[12 + j] = fmaf(fexp2(dlt * Aj2[12 + j]), h[12 + j], du * bq3[j]);
    }
  }

  float4v* hv = (float4v*)stslot(xz, (chain * NC + c) * DS);
#pragma unroll
  for (int q = 0; q < 4; ++q) {
    float4v v;
#pragma unroll
    for (int j = 0; j < 4; ++j) v[j] = h[q * 4 + j];
    hv[q] = v;
  }
  *sumd_slot(xdbl, chain * NC + c) = sd;
}

__global__ __launch_bounds__(256) void scan_fix(
    bf16* __restrict__ xz, const float* __restrict__ xdbl,
    const float* __restrict__ A_log) {
  int lane = threadIdx.x & 15;
  int chain = blockIdx.x * 16 + (threadIdx.x >> 4);
  int d = chain & (DI - 1);
  float Aj2 = -__expf(A_log[d * DS + lane]) * LOG2E;
  float carry = 0.f;
#pragma unroll 4
  for (int c = 0; c < NC; ++c) {
    float* hp = stslot(xz, (chain * NC + c) * DS + lane);
    float sd = *sumd_slot((float*)xdbl, chain * NC + c);
    float he = *hp;
    *hp = carry;
    carry = fmaf(fexp2(Aj2 * sd), carry, he);
  }
}

__global__ __launch_bounds__(256) void scan_final(
    const bf16* __restrict__ delta, bf16* __restrict__ u,
    const float* __restrict__ xdbl, bf16* __restrict__ xz,
    const float* __restrict__ A_log, const float* __restrict__ Dp) {
  __shared__ float lds_bc[CL * 2 * DS];   // 32 x 32 f32 = 4 KB
  int tid = threadIdx.x;
  int g = blockIdx.x * 256 + tid;
  int d = g & (DI - 1);
  int b = (g >> 11) & (BB - 1);
  int c = g >> 13;
  int chain = (b << 11) | d;
  int t0 = b * LL + c * CL;

  if (tid < CL * 4) {
    int row = tid >> 2, col0 = (tid & 3) * 8;
    const float4v* src = (const float4v*)&xdbl[(size_t)(t0 + row) * 96 + DR + col0];
    *(float4v*)&lds_bc[row * 32 + col0] = src[0];
    *(float4v*)&lds_bc[row * 32 + col0 + 4] = src[1];
  }

  float Aj2[DS];
  const float4v* Ap = (const float4v*)&A_log[d * DS];
#pragma unroll
  for (int i = 0; i < 4; ++i) {
    float4v v = Ap[i];
#pragma unroll
    for (int j = 0; j < 4; ++j) Aj2[i * 4 + j] = -__expf(v[j]) * LOG2E;
  }
  float Dd = Dp[d];

  float h[DS];
  const float4v* hv = (const float4v*)stslot(xz, (chain * NC + c) * DS);
#pragma unroll
  for (int q = 0; q < 4; ++q) {
    float4v v = hv[q];
#pragma unroll
    for (int j = 0; j < 4; ++j) h[q * 4 + j] = v[j];
  }

  const bf16* dp = delta + (size_t)t0 * DI + d;
  bf16* uw = u + (size_t)t0 * DI + d;
  const bf16* zp = xz + (size_t)t0 * (2 * DI) + DI + d;
  __syncthreads();

#pragma unroll 2
  for (int i = 0; i < CL; ++i) {
    float dlt = cvt(*dp); dp += DI;
    float ut = cvt(*uw);
    float zt = cvt(*zp); zp += 2 * DI;
    const float4v* Bp = (const float4v*)&lds_bc[i * 32];
    float4v b0 = Bp[0], b1 = Bp[1], b2 = Bp[2], b3 = Bp[3];
    float4v c0 = Bp[4], c1 = Bp[5], c2 = Bp[6], c3 = Bp[7];
    float du = dlt * ut;
    float yp = 0.f;
#pragma unroll
    for (int j = 0; j < 4; ++j) {
      h[j]      = fmaf(fexp2(dlt * Aj2[j]),      h[j],      du * b0[j]);
      h[4 + j]  = fmaf(fexp2(dlt * Aj2[4 + j]),  h[4 + j],  du * b1[j]);
      h[8 + j]  = fmaf(fexp2(dlt * Aj2[8 + j]),  h[8 + j],  du * b2[j]);
      h[12 + j] = fmaf(fexp2(dlt * Aj2[12 + j]), h[12 + j], du * b3[j]);
      yp = fmaf(h[j], c0[j], yp);
      yp = fmaf(h[4 + j], c1[j], yp);
      yp = fmaf(h[8 + j], c2[j], yp);
      yp = fmaf(h[12 + j], c3[j], yp);
    }
    float gte = zt / (1.f + __expf(-zt));
    stv(uw, (yp + ut * Dd) * gte);
    uw += DI;
  }
}

// ---------------------------------------------------------------------------
extern "C" void kernel_launch(void* const* d_in, const int* in_sizes, int n_in,
                              void* d_out, int out_size, void* d_ws, size_t ws_size,
                              hipStream_t stream) {
  const float* hidden    = (const float*)d_in[0];
  const float* in_proj_w = (const float*)d_in[1];
  const float* conv_w    = (const float*)d_in[2];
  const float* conv_b    = (const float*)d_in[3];
  const float* x_proj_w  = (const float*)d_in[4];
  const float* dt_proj_w = (const float*)d_in[5];
  const float* dt_proj_b = (const float*)d_in[6];
  const float* A_log     = (const float*)d_in[7];
  const float* D_param   = (const float*)d_in[8];
  const float* out_proj_w= (const float*)d_in[9];
  float* out = (float*)d_out;

  // Workspace (131 MB, proven):
  //   xz 64MB bf16 | u 32MB bf16 | xdbl 3MB f32 | delta 32MB bf16
  size_t need = (size_t)TT * 4096 * sizeof(bf16) + (size_t)TT * DI * sizeof(bf16)
              + (size_t)TT * (DR + 2 * DS) * sizeof(float) + (size_t)TT * DI * sizeof(bf16);
  if (ws_size < need) return;

  bf16* xz     = (bf16*)d_ws;
  bf16* u      = xz + (size_t)TT * 2 * DI;
  float* xdbl  = (float*)(u + (size_t)TT * DI);
  bf16* delta  = (bf16*)(xdbl + (size_t)TT * (DR + 2 * DS));

  bf16* hbf   = u;                         // 8192x1024 bf16 (16MB)
  bf16* wbf   = u + (size_t)TT * DM;       // 4096x1024 bf16 (8MB)
  bf16* wx_bf = delta;                     // 96x2048 bf16, dead at step 4
  bf16* opbf  = delta;                     // 1024x2048 bf16, written at 5b

  dim3 blk(256);

  // 0) pre-convert inputs/weights to bf16
  cvt_bf16<<<dim3(TT * DM / 8 / 256), blk, 0, stream>>>(hidden, hbf, TT * DM / 8);
  cvt_bf16<<<dim3(2 * DI * DM / 8 / 256), blk, 0, stream>>>(in_proj_w, wbf, 2 * DI * DM / 8);
  cvt_bf16<<<dim3(96 * DI / 8 / 256), blk, 0, stream>>>(x_proj_w, wx_bf, 96 * DI / 8);

  // 1) xz = hidden @ in_proj_w^T   (dbuf bf16 GEMM)
  gemm_bf16<bf16><<<dim3(4096 / 128, TT / 128), blk, 0, stream>>>(
      hbf, DM, wbf, DM, xz, 2 * DI, DM);

  // 2) u = silu(causal_conv(x) + cb)
  conv_silu<<<dim3(TT), blk, 0, stream>>>(xz, conv_w, conv_b, u);

  // 3) x_dbl = u @ x_proj_w^T      (MFMA split-K)
  xproj_splitk<<<dim3(TT / 128, SK), blk, 0, stream>>>(u, wx_bf, xz);
  xproj_reduce<<<dim3(TT * 96 / 256), blk, 0, stream>>>(xz, xdbl);

  // 4) delta = softplus(x_dbl[:, :64] @ dt_proj_w^T + b)
  gemm_mfma<float, bf16, 1><<<dim3(DI / 128, TT / 128), blk, 0, stream>>>(
      xdbl, DR + 2 * DS, dt_proj_w, DR, dt_proj_b, delta, DI, DR);

  // 5) chunked selective scan (NC=64); y -> in-place into u
  scan_local<<<dim3(8192 * NC / 256), blk, 0, stream>>>(delta, u, xdbl, xz, A_log);
  scan_fix<<<dim3(8192 / 16), blk, 0, stream>>>(xz, xdbl, A_log);
  scan_final<<<dim3(8192 * NC / 256), blk, 0, stream>>>(delta, u, xdbl, xz, A_log, D_param);

  // 5b) convert out_proj_w -> bf16
  cvt_bf16<<<dim3(DM * DI / 8 / 256), blk, 0, stream>>>(out_proj_w, opbf, DM * DI / 8);

  // 6) out = y @ out_proj_w^T      (dbuf bf16 GEMM)
  gemm_bf16<float><<<dim3(DM / 128, TT / 128), blk, 0, stream>>>(
      u, DI, opbf, DI, out, DM, DI);
}